// Round 1
// baseline (280.365 us; speedup 1.0000x reference)
//
#include <hip/hip_runtime.h>

#define DD    2048
#define KK    256
#define NS    256
#define BB    64
#define NBINS 4096
#define CAND_MAX 512

// Map float bits to order-preserving unsigned: larger float <-> larger uint.
__device__ __forceinline__ uint32_t orderable(float f) {
    uint32_t b = __float_as_uint(f);
    return (b & 0x80000000u) ? ~b : (b | 0x80000000u);
}

__global__ __launch_bounds__(256) void topk_count_kernel(
    const float* __restrict__ x,
    const float* __restrict__ noise,
    float* __restrict__ outTop)   // [BB][DD] counts, pre-zeroed
{
    const int tid = threadIdx.x;
    const int bs  = blockIdx.x;          // 0 .. BB*NS-1
    const int b   = bs >> 8;             // / NS
    const int s   = bs & (NS - 1);

    __shared__ uint32_t hist[NBINS];
    __shared__ uint32_t ssum[256];
    __shared__ uint32_t cand_v[CAND_MAX];
    __shared__ uint32_t cand_d[CAND_MAX];
    __shared__ uint32_t sh_candCount;
    __shared__ uint32_t sh_tb;
    __shared__ uint32_t sh_R;

    // ---- zero histogram (uint4 stores) ----
    uint4* h4 = (uint4*)hist;
    #pragma unroll
    for (int i = 0; i < 4; ++i) h4[tid + i * 256] = make_uint4(0u, 0u, 0u, 0u);
    if (tid == 0) sh_candCount = 0u;
    __syncthreads();

    // ---- load 8 values/thread, bucket into histogram ----
    const float4* xr = (const float4*)(x + (size_t)b * DD);
    const float4* nr = (const float4*)(noise + ((size_t)b * NS + s) * DD);

    uint32_t u[8];
    #pragma unroll
    for (int kq = 0; kq < 2; ++kq) {
        float4 xv = xr[tid * 2 + kq];
        float4 nv = nr[tid * 2 + kq];
        u[kq * 4 + 0] = orderable(fmaf(nv.x, 0.05f, xv.x));
        u[kq * 4 + 1] = orderable(fmaf(nv.y, 0.05f, xv.y));
        u[kq * 4 + 2] = orderable(fmaf(nv.z, 0.05f, xv.z));
        u[kq * 4 + 3] = orderable(fmaf(nv.w, 0.05f, xv.w));
    }
    #pragma unroll
    for (int e = 0; e < 8; ++e)
        atomicAdd(&hist[u[e] >> 20], 1u);
    __syncthreads();

    // ---- segmented suffix sum over 4096 bins: thread tid owns bins [tid*16, tid*16+16) ----
    uint32_t seg = 0;
    {
        const uint4* hseg = (const uint4*)hist;
        #pragma unroll
        for (int i = 0; i < 4; ++i) {
            uint4 hv = hseg[tid * 4 + i];
            seg += hv.x + hv.y + hv.z + hv.w;
        }
    }
    ssum[tid] = seg;
    __syncthreads();
    // inclusive suffix scan (Hillis-Steele)
    for (int st = 1; st < 256; st <<= 1) {
        uint32_t add = (tid + st < 256) ? ssum[tid + st] : 0u;
        __syncthreads();
        ssum[tid] += add;
        __syncthreads();
    }
    uint32_t incl  = ssum[tid];          // count of elements with bucket >= tid*16
    uint32_t above = incl - seg;         // count of elements with bucket >= (tid+1)*16

    // exactly one thread has the crossing K inside its segment
    if (above < KK && incl >= KK) {
        uint32_t c = above;
        for (int bin = tid * 16 + 15; bin >= tid * 16; --bin) {
            uint32_t h = hist[bin];
            if (c + h >= KK) { sh_tb = (uint32_t)bin; sh_R = KK - c; break; }
            c += h;
        }
    }
    __syncthreads();
    const uint32_t tb = sh_tb;
    const uint32_t R  = sh_R;

    // ---- classify: bucket > tb => winner; bucket == tb => candidate ----
    float* rowOut = outTop + (size_t)b * DD;
    #pragma unroll
    for (int e = 0; e < 8; ++e) {
        uint32_t bkt = u[e] >> 20;
        int d = tid * 8 + e;
        if (bkt > tb) {
            atomicAdd(&rowOut[d], 1.0f);
        } else if (bkt == tb) {
            uint32_t j = atomicAdd(&sh_candCount, 1u);
            if (j < CAND_MAX) { cand_v[j] = u[e]; cand_d[j] = (uint32_t)d; }
        }
    }
    __syncthreads();

    // ---- exact rank-select top R among candidates (tie-break by d: deterministic) ----
    uint32_t M = sh_candCount;
    if (M > CAND_MAX) M = CAND_MAX;
    for (uint32_t j = tid; j < M; j += 256) {
        uint32_t v  = cand_v[j];
        uint32_t dj = cand_d[j];
        uint32_t r  = 0;
        for (uint32_t i = 0; i < M; ++i) {
            uint32_t vi = cand_v[i];
            r += (vi > v) || (vi == v && cand_d[i] < dj);
        }
        if (r < R) atomicAdd(&rowOut[dj], 1.0f);
    }
}

__global__ __launch_bounds__(256) void finalize_kernel(float* __restrict__ out) {
    int i = blockIdx.x * 256 + threadIdx.x;   // 0 .. BB*DD-1
    float c = out[i];
    float t = c * (1.0f / 256.0f);
    out[i] = t;
    out[BB * DD + i] = 1.0f - t;
}

extern "C" void kernel_launch(void* const* d_in, const int* in_sizes, int n_in,
                              void* d_out, int out_size, void* d_ws, size_t ws_size,
                              hipStream_t stream) {
    const float* x     = (const float*)d_in[0];
    const float* noise = (const float*)d_in[1];
    float* out = (float*)d_out;

    // zero the counts half of the output (we accumulate into it)
    hipMemsetAsync(out, 0, (size_t)BB * DD * sizeof(float), stream);

    topk_count_kernel<<<BB * NS, 256, 0, stream>>>(x, noise, out);
    finalize_kernel<<<(BB * DD) / 256, 256, 0, stream>>>(out);
}

// Round 2
// 113.477 us; speedup vs baseline: 2.4707x; 2.4707x over previous
//
#include <hip/hip_runtime.h>

#define DD    2048
#define KK    256
#define NS    256
#define BB    64
#define NBINS 4096
#define SPG   8              // samples per group (per block)
#define NG    (NS / SPG)     // 32 groups per b
#define CAND_MAX 512

// Map float bits to order-preserving unsigned: larger float <-> larger uint.
__device__ __forceinline__ uint32_t orderable(float f) {
    uint32_t u = __float_as_uint(f);
    return (u & 0x80000000u) ? ~u : (u | 0x80000000u);
}

// One block per (b, group of SPG samples). Accumulates winner counts for the
// group in LDS, then writes u8 partial counts to ws (USE_WS=1) or atomically
// adds float counts to outCounts (fallback).
template <int USE_WS>
__global__ __launch_bounds__(256) void topk_group_kernel(
    const float* __restrict__ x,
    const float* __restrict__ noise,
    unsigned char* __restrict__ ws,      // [BB][NG][DD] u8
    float* __restrict__ outCounts)       // [BB][DD] f32 (fallback, pre-zeroed)
{
    const int tid  = threadIdx.x;
    const int bg   = blockIdx.x;
    const int b    = bg >> 5;            // / NG (NG=32)
    const int g    = bg & (NG - 1);
    const int lane = tid & 63;
    const int wid  = tid >> 6;

    __shared__ uint32_t hist[NBINS];     // 16 KB
    __shared__ uint32_t counts[DD];      // 8 KB
    __shared__ uint32_t wsum[4];
    __shared__ uint32_t cand_v[CAND_MAX];
    __shared__ uint32_t cand_d[CAND_MAX];
    __shared__ uint32_t sh_candCount;
    __shared__ uint32_t sh_tb, sh_R;

    // ---- zero hist + counts ----
    const uint4 z = make_uint4(0u, 0u, 0u, 0u);
    uint4* h4 = (uint4*)hist;
    #pragma unroll
    for (int i = 0; i < 4; ++i) h4[tid + i * 256] = z;
    uint4* c4 = (uint4*)counts;
    #pragma unroll
    for (int i = 0; i < 2; ++i) c4[tid + i * 256] = z;
    if (tid == 0) sh_candCount = 0u;

    // ---- x row -> registers (shared by all SPG samples) ----
    const float4* xr = (const float4*)(x + (size_t)b * DD);
    const float4 xv0 = xr[tid * 2 + 0];
    const float4 xv1 = xr[tid * 2 + 1];

    const float4* nbase =
        (const float4*)(noise + ((size_t)b * NS + (size_t)g * SPG) * DD);
    // prefetch sample 0's noise row
    float4 nv0 = nbase[tid * 2 + 0];
    float4 nv1 = nbase[tid * 2 + 1];

    __syncthreads();

    for (int s = 0; s < SPG; ++s) {
        // ---- keys for this sample ----
        uint32_t u[8];
        u[0] = orderable(fmaf(nv0.x, 0.05f, xv0.x));
        u[1] = orderable(fmaf(nv0.y, 0.05f, xv0.y));
        u[2] = orderable(fmaf(nv0.z, 0.05f, xv0.z));
        u[3] = orderable(fmaf(nv0.w, 0.05f, xv0.w));
        u[4] = orderable(fmaf(nv1.x, 0.05f, xv1.x));
        u[5] = orderable(fmaf(nv1.y, 0.05f, xv1.y));
        u[6] = orderable(fmaf(nv1.z, 0.05f, xv1.z));
        u[7] = orderable(fmaf(nv1.w, 0.05f, xv1.w));

        // ---- prefetch next sample's noise row ----
        if (s + 1 < SPG) {
            const float4* nr = nbase + (size_t)(s + 1) * (DD / 4);
            nv0 = nr[tid * 2 + 0];
            nv1 = nr[tid * 2 + 1];
        }

        // ---- histogram on top 12 bits ----
        #pragma unroll
        for (int e = 0; e < 8; ++e)
            atomicAdd(&hist[u[e] >> 20], 1u);
        __syncthreads();                                   // B1

        // ---- segmented suffix sum: thread owns bins [tid*16, tid*16+16) ----
        uint32_t seg = 0;
        {
            const uint4* hseg = (const uint4*)hist;
            #pragma unroll
            for (int i = 0; i < 4; ++i) {
                uint4 hv = hseg[tid * 4 + i];
                seg += hv.x + hv.y + hv.z + hv.w;
            }
        }
        // wave-level inclusive suffix scan (Hillis-Steele via shfl_down)
        uint32_t sfx = seg;
        #pragma unroll
        for (int st = 1; st < 64; st <<= 1) {
            uint32_t o = __shfl_down(sfx, (unsigned)st, 64);
            if (lane + st < 64) sfx += o;
        }
        if (lane == 0) wsum[wid] = sfx;
        __syncthreads();                                   // B2
        uint32_t hi = 0;
        #pragma unroll
        for (int w = 0; w < 4; ++w)
            if (w > wid) hi += wsum[w];
        const uint32_t incl  = sfx + hi;   // elements with bucket >= tid*16
        const uint32_t above = incl - seg; // elements with bucket >= (tid+1)*16

        // exactly one thread holds the crossing
        if (above < KK && incl >= KK) {
            uint32_t c = above;
            for (int bin = tid * 16 + 15;; --bin) {
                uint32_t h = hist[bin];
                if (c + h >= KK) { sh_tb = (uint32_t)bin; sh_R = KK - c; break; }
                c += h;
            }
        }
        __syncthreads();                                   // B3
        const uint32_t tb = sh_tb;
        const uint32_t R  = sh_R;

        // ---- classify (owner-thread counts: plain add) + zero hist ----
        #pragma unroll
        for (int e = 0; e < 8; ++e) {
            uint32_t bkt = u[e] >> 20;
            if (bkt > tb) {
                counts[tid * 8 + e] += 1u;        // exclusive owner
            } else if (bkt == tb) {
                uint32_t j = atomicAdd(&sh_candCount, 1u);
                if (j < CAND_MAX) { cand_v[j] = u[e]; cand_d[j] = (uint32_t)(tid * 8 + e); }
            }
        }
        #pragma unroll
        for (int i = 0; i < 4; ++i) h4[tid + i * 256] = z; // hist reads done at B3
        __syncthreads();                                   // B4

        // ---- exact rank-select top R among candidates (tie-break by d) ----
        uint32_t M = sh_candCount;
        if (M > CAND_MAX) M = CAND_MAX;
        for (uint32_t j = tid; j < M; j += 256) {
            uint32_t v  = cand_v[j];
            uint32_t dj = cand_d[j];
            uint32_t r  = 0;
            for (uint32_t i = 0; i < M; ++i) {
                uint32_t vi = cand_v[i];
                r += (vi > v) || (vi == v && cand_d[i] < dj);
            }
            if (r < R) atomicAdd(&counts[dj], 1u);
        }
        __syncthreads();                                   // B5
        if (tid == 0) sh_candCount = 0u;  // visible by next iter's B1..B3
    }

    // ---- write group partial counts ----
    if (USE_WS) {
        uint32_t* w32 = (uint32_t*)(ws + ((size_t)b * NG + g) * DD);
        #pragma unroll
        for (int q = 0; q < 2; ++q) {
            uint32_t p = 0;
            #pragma unroll
            for (int e = 0; e < 4; ++e)
                p |= (counts[tid * 8 + q * 4 + e] & 0xFFu) << (8 * e);
            w32[tid * 2 + q] = p;
        }
    } else {
        float* rowOut = outCounts + (size_t)b * DD;
        #pragma unroll
        for (int e = 0; e < 8; ++e) {
            uint32_t c = counts[tid * 8 + e];
            if (c) atomicAdd(&rowOut[tid * 8 + e], (float)c);
        }
    }
}

// Sum NG u8 partials per (b,d), normalize, write both output halves.
__global__ __launch_bounds__(256) void reduce_kernel(
    const unsigned char* __restrict__ ws, float* __restrict__ out)
{
    int idx = blockIdx.x * 256 + threadIdx.x;  // 0 .. BB*DD/4-1
    int b   = idx / (DD / 4);
    int dq  = idx - b * (DD / 4);
    const unsigned char* base = ws + (size_t)b * NG * DD + (size_t)dq * 4;
    uint32_t s0 = 0, s1 = 0, s2 = 0, s3 = 0;
    #pragma unroll
    for (int g = 0; g < NG; ++g) {
        uint32_t p = *(const uint32_t*)(base + (size_t)g * DD);
        s0 += p & 0xFFu; s1 += (p >> 8) & 0xFFu;
        s2 += (p >> 16) & 0xFFu; s3 += (p >> 24) & 0xFFu;
    }
    const float inv = 1.0f / 256.0f;
    float4 t = make_float4(s0 * inv, s1 * inv, s2 * inv, s3 * inv);
    *(float4*)(out + (size_t)b * DD + dq * 4) = t;
    *(float4*)(out + (size_t)(BB * DD) + (size_t)b * DD + dq * 4) =
        make_float4(1.0f - t.x, 1.0f - t.y, 1.0f - t.z, 1.0f - t.w);
}

// Fallback finalize (only when ws is too small): counts -> (topk, 1-topk).
__global__ __launch_bounds__(256) void finalize_kernel(float* __restrict__ out) {
    int i = blockIdx.x * 256 + threadIdx.x;  // 0 .. BB*DD-1
    float t = out[i] * (1.0f / 256.0f);
    out[i] = t;
    out[BB * DD + i] = 1.0f - t;
}

extern "C" void kernel_launch(void* const* d_in, const int* in_sizes, int n_in,
                              void* d_out, int out_size, void* d_ws, size_t ws_size,
                              hipStream_t stream) {
    const float* x     = (const float*)d_in[0];
    const float* noise = (const float*)d_in[1];
    float* out = (float*)d_out;

    const size_t ws_needed = (size_t)BB * NG * DD;  // 4 MB of u8 partials
    if (ws_size >= ws_needed) {
        unsigned char* ws8 = (unsigned char*)d_ws;
        topk_group_kernel<1><<<BB * NG, 256, 0, stream>>>(x, noise, ws8, nullptr);
        reduce_kernel<<<(BB * DD / 4) / 256, 256, 0, stream>>>(ws8, out);
    } else {
        hipMemsetAsync(out, 0, (size_t)BB * DD * sizeof(float), stream);
        topk_group_kernel<0><<<BB * NG, 256, 0, stream>>>(x, noise, nullptr, out);
        finalize_kernel<<<(BB * DD) / 256, 256, 0, stream>>>(out);
    }
}

// Round 3
// 104.531 us; speedup vs baseline: 2.6821x; 1.0856x over previous
//
#include <hip/hip_runtime.h>

#define DD    2048
#define KK    256
#define NS    256
#define BB    64
#define SPG   8              // samples per group (per block)
#define NG    (NS / SPG)     // 32 groups per b
#define NSEG  256            // 256 segments x 16 bins = 4096 buckets
#define SEGW  17             // padded segment width (odd -> conflict-free)
#define CAND_MAX 512

// Map float bits to order-preserving unsigned: larger float <-> larger uint.
__device__ __forceinline__ uint32_t orderable(float f) {
    uint32_t u = __float_as_uint(f);
    return (u & 0x80000000u) ? ~u : (u | 0x80000000u);
}

// One block per (b, group of SPG samples). Accumulates winner counts for the
// group in LDS, writes u8 partial counts to ws (USE_WS=1) or atomically adds
// float counts to outCounts (fallback).
template <int USE_WS>
__global__ __launch_bounds__(256) void topk_group_kernel(
    const float* __restrict__ x,
    const float* __restrict__ noise,
    unsigned char* __restrict__ ws,      // [BB][NG][DD] u8
    float* __restrict__ outCounts)       // [BB][DD] f32 (fallback, pre-zeroed)
{
    const int tid  = threadIdx.x;
    const int bg   = blockIdx.x;
    const int b    = bg >> 5;            // / NG (NG=32)
    const int g    = bg & (NG - 1);
    const int lane = tid & 63;
    const int wid  = tid >> 6;

    __shared__ uint32_t hist[NSEG * SEGW];   // 17408 B, padded segments
    __shared__ uint32_t counts[DD];          // 8192 B
    __shared__ uint32_t wsum[4];
    __shared__ uint32_t cand_v[CAND_MAX];
    __shared__ uint32_t cand_d[CAND_MAX];
    __shared__ uint32_t candCnt[2];
    __shared__ uint32_t sh_tb, sh_R;

    // ---- zero hist (padded) + counts ----
    #pragma unroll
    for (int i = 0; i < SEGW; ++i) hist[tid * SEGW + i] = 0u;
    const uint4 z = make_uint4(0u, 0u, 0u, 0u);
    uint4* c4 = (uint4*)counts;
    #pragma unroll
    for (int i = 0; i < 2; ++i) c4[tid + i * 256] = z;
    if (tid == 0) { candCnt[0] = 0u; candCnt[1] = 0u; }

    // ---- x row -> registers (shared by all SPG samples) ----
    const float4* xr = (const float4*)(x + (size_t)b * DD);
    const float4 xv0 = xr[tid * 2 + 0];
    const float4 xv1 = xr[tid * 2 + 1];

    const float4* nbase =
        (const float4*)(noise + ((size_t)b * NS + (size_t)g * SPG) * DD);
    // prefetch sample 0's noise row
    float4 nv0 = nbase[tid * 2 + 0];
    float4 nv1 = nbase[tid * 2 + 1];

    __syncthreads();

    for (int s = 0; s < SPG; ++s) {
        // ---- keys for this sample (registers) ----
        uint32_t u[8];
        u[0] = orderable(fmaf(nv0.x, 0.05f, xv0.x));
        u[1] = orderable(fmaf(nv0.y, 0.05f, xv0.y));
        u[2] = orderable(fmaf(nv0.z, 0.05f, xv0.z));
        u[3] = orderable(fmaf(nv0.w, 0.05f, xv0.w));
        u[4] = orderable(fmaf(nv1.x, 0.05f, xv1.x));
        u[5] = orderable(fmaf(nv1.y, 0.05f, xv1.y));
        u[6] = orderable(fmaf(nv1.z, 0.05f, xv1.z));
        u[7] = orderable(fmaf(nv1.w, 0.05f, xv1.w));

        // ---- prefetch next sample's noise row ----
        if (s + 1 < SPG) {
            const float4* nr = nbase + (size_t)(s + 1) * (DD / 4);
            nv0 = nr[tid * 2 + 0];
            nv1 = nr[tid * 2 + 1];
        }

        // ---- histogram on top 12 bits (padded scatter) ----
        #pragma unroll
        for (int e = 0; e < 8; ++e) {
            uint32_t bkt = u[e] >> 20;
            atomicAdd(&hist[(bkt >> 4) * SEGW + (bkt & 15u)], 1u);
        }
        __syncthreads();                                   // B1

        // reset the parity counter the NEXT sample will use (last read
        // finished before the previous B1; next write is after B3)
        if (tid == 0) candCnt[(s + 1) & 1] = 0u;

        // ---- read own segment (conflict-free, odd stride) into registers ----
        uint32_t h[16];
        #pragma unroll
        for (int i = 0; i < 16; ++i) h[i] = hist[tid * SEGW + i];
        uint32_t seg = 0;
        #pragma unroll
        for (int i = 0; i < 16; ++i) seg += h[i];

        // wave-level inclusive suffix scan (register shuffles)
        uint32_t sfx = seg;
        #pragma unroll
        for (int st = 1; st < 64; st <<= 1) {
            uint32_t o = __shfl_down(sfx, (unsigned)st, 64);
            if (lane + st < 64) sfx += o;
        }
        if (lane == 0) wsum[wid] = sfx;
        __syncthreads();                                   // B2
        uint32_t hi = 0;
        #pragma unroll
        for (int w = 0; w < 4; ++w)
            if (w > wid) hi += wsum[w];
        const uint32_t incl  = sfx + hi;   // elements with bucket >= tid*16
        const uint32_t above = incl - seg; // elements with bucket >= (tid+1)*16

        // ---- crossing search: register-only, fully unrolled ----
        if (above < KK && incl >= KK) {
            uint32_t c = above;
            #pragma unroll
            for (int i = 15; i >= 0; --i) {
                uint32_t hh = h[i];
                if (c + hh >= KK) { sh_tb = (uint32_t)(tid * 16 + i); sh_R = KK - c; break; }
                c += hh;
            }
        }
        __syncthreads();                                   // B3
        const uint32_t tb = sh_tb;
        const uint32_t R  = sh_R;
        const uint32_t par = (uint32_t)(s & 1);

        // ---- classify (owner-thread counts) + scatter-zero own hist bins ----
        #pragma unroll
        for (int e = 0; e < 8; ++e) {
            uint32_t bkt = u[e] >> 20;
            if (bkt > tb) {
                counts[tid * 8 + e] += 1u;        // exclusive owner
            } else if (bkt == tb) {
                uint32_t j = atomicAdd(&candCnt[par], 1u);
                if (j < CAND_MAX) { cand_v[j] = u[e]; cand_d[j] = (uint32_t)(tid * 8 + e); }
            }
        }
        #pragma unroll
        for (int e = 0; e < 8; ++e) {
            uint32_t bkt = u[e] >> 20;
            hist[(bkt >> 4) * SEGW + (bkt & 15u)] = 0u;   // duplicates benign
        }
        __syncthreads();                                   // B4

        // ---- exact rank-select top R among candidates (tie-break by d) ----
        uint32_t M = candCnt[par];
        if (M > CAND_MAX) M = CAND_MAX;
        for (uint32_t j = tid; j < M; j += 256) {
            uint32_t v  = cand_v[j];
            uint32_t dj = cand_d[j];
            uint32_t r  = 0;
            for (uint32_t i = 0; i < M; ++i) {
                uint32_t vi = cand_v[i];
                r += (vi > v) || (vi == v && cand_d[i] < dj);
            }
            if (r < R) atomicAdd(&counts[dj], 1u);
        }
        // no trailing barrier: next sample's B1 orders rank-adds vs classify
    }
    __syncthreads();   // ensure last sample's rank-adds land before readout

    // ---- write group partial counts ----
    if (USE_WS) {
        uint32_t* w32 = (uint32_t*)(ws + ((size_t)b * NG + g) * DD);
        #pragma unroll
        for (int q = 0; q < 2; ++q) {
            uint32_t p = 0;
            #pragma unroll
            for (int e = 0; e < 4; ++e)
                p |= (counts[tid * 8 + q * 4 + e] & 0xFFu) << (8 * e);
            w32[tid * 2 + q] = p;
        }
    } else {
        float* rowOut = outCounts + (size_t)b * DD;
        #pragma unroll
        for (int e = 0; e < 8; ++e) {
            uint32_t c = counts[tid * 8 + e];
            if (c) atomicAdd(&rowOut[tid * 8 + e], (float)c);
        }
    }
}

// Sum NG u8 partials per (b,d), normalize, write both output halves.
__global__ __launch_bounds__(256) void reduce_kernel(
    const unsigned char* __restrict__ ws, float* __restrict__ out)
{
    int idx = blockIdx.x * 256 + threadIdx.x;  // 0 .. BB*DD/4-1
    int b   = idx / (DD / 4);
    int dq  = idx - b * (DD / 4);
    const unsigned char* base = ws + (size_t)b * NG * DD + (size_t)dq * 4;
    uint32_t s0 = 0, s1 = 0, s2 = 0, s3 = 0;
    #pragma unroll
    for (int g = 0; g < NG; ++g) {
        uint32_t p = *(const uint32_t*)(base + (size_t)g * DD);
        s0 += p & 0xFFu; s1 += (p >> 8) & 0xFFu;
        s2 += (p >> 16) & 0xFFu; s3 += (p >> 24) & 0xFFu;
    }
    const float inv = 1.0f / 256.0f;
    float4 t = make_float4(s0 * inv, s1 * inv, s2 * inv, s3 * inv);
    *(float4*)(out + (size_t)b * DD + dq * 4) = t;
    *(float4*)(out + (size_t)(BB * DD) + (size_t)b * DD + dq * 4) =
        make_float4(1.0f - t.x, 1.0f - t.y, 1.0f - t.z, 1.0f - t.w);
}

// Fallback finalize (only when ws is too small): counts -> (topk, 1-topk).
__global__ __launch_bounds__(256) void finalize_kernel(float* __restrict__ out) {
    int i = blockIdx.x * 256 + threadIdx.x;  // 0 .. BB*DD-1
    float t = out[i] * (1.0f / 256.0f);
    out[i] = t;
    out[BB * DD + i] = 1.0f - t;
}

extern "C" void kernel_launch(void* const* d_in, const int* in_sizes, int n_in,
                              void* d_out, int out_size, void* d_ws, size_t ws_size,
                              hipStream_t stream) {
    const float* x     = (const float*)d_in[0];
    const float* noise = (const float*)d_in[1];
    float* out = (float*)d_out;

    const size_t ws_needed = (size_t)BB * NG * DD;  // 4 MB of u8 partials
    if (ws_size >= ws_needed) {
        unsigned char* ws8 = (unsigned char*)d_ws;
        topk_group_kernel<1><<<BB * NG, 256, 0, stream>>>(x, noise, ws8, nullptr);
        reduce_kernel<<<(BB * DD / 4) / 256, 256, 0, stream>>>(ws8, out);
    } else {
        hipMemsetAsync(out, 0, (size_t)BB * DD * sizeof(float), stream);
        topk_group_kernel<0><<<BB * NG, 256, 0, stream>>>(x, noise, nullptr, out);
        finalize_kernel<<<(BB * DD) / 256, 256, 0, stream>>>(out);
    }
}

// Round 4
// 60.888 us; speedup vs baseline: 4.6046x; 1.7168x over previous
//
#include <hip/hip_runtime.h>

#define DD    2048
#define KK    256
#define NS    256
#define BB    64
#define SPG   8              // samples per group (per block)
#define NG    (NS / SPG)     // 32 groups per b
#define NBIN  256            // fine-window bins (one per thread)
#define WHALF 1.0f           // window half-width around t_est
#define CAND_MAX 128
// precompute (threshold-estimate) kernel: 4096 coarse bins, padded segments
#define PSEGW 17

// Map float bits to order-preserving unsigned, and back.
__device__ __forceinline__ uint32_t orderable(float f) {
    uint32_t u = __float_as_uint(f);
    return (u & 0x80000000u) ? ~u : (u | 0x80000000u);
}
__device__ __forceinline__ float inv_orderable(uint32_t u) {
    return (u & 0x80000000u) ? __uint_as_float(u & 0x7FFFFFFFu)
                             : __uint_as_float(~u);
}

// Per-b approximate top-K threshold of x (lower edge of the crossing 12-bit
// bucket; error < one bucket width). One block per b.
__global__ __launch_bounds__(256) void thresh_kernel(
    const float* __restrict__ x, float* __restrict__ tEst)
{
    const int tid  = threadIdx.x;
    const int b    = blockIdx.x;
    const int lane = tid & 63;
    const int wid  = tid >> 6;
    __shared__ uint32_t hist[256 * PSEGW];
    __shared__ uint32_t wsum[4];

    #pragma unroll
    for (int i = 0; i < PSEGW; ++i) hist[tid * PSEGW + i] = 0u;
    __syncthreads();

    const float4* xr = (const float4*)(x + (size_t)b * DD);
    float4 a0 = xr[tid * 2 + 0], a1 = xr[tid * 2 + 1];
    uint32_t u[8];
    u[0] = orderable(a0.x); u[1] = orderable(a0.y);
    u[2] = orderable(a0.z); u[3] = orderable(a0.w);
    u[4] = orderable(a1.x); u[5] = orderable(a1.y);
    u[6] = orderable(a1.z); u[7] = orderable(a1.w);
    #pragma unroll
    for (int e = 0; e < 8; ++e) {
        uint32_t bkt = u[e] >> 20;
        atomicAdd(&hist[(bkt >> 4) * PSEGW + (bkt & 15u)], 1u);
    }
    __syncthreads();

    uint32_t h[16], seg = 0;
    #pragma unroll
    for (int i = 0; i < 16; ++i) { h[i] = hist[tid * PSEGW + i]; seg += h[i]; }
    uint32_t sfx = seg;
    #pragma unroll
    for (int st = 1; st < 64; st <<= 1) {
        uint32_t o = __shfl_down(sfx, (unsigned)st, 64);
        if (lane + st < 64) sfx += o;
    }
    if (lane == 0) wsum[wid] = sfx;
    __syncthreads();
    uint32_t hi = 0;
    #pragma unroll
    for (int w = 0; w < 4; ++w) if (w > wid) hi += wsum[w];
    const uint32_t incl  = sfx + hi;
    const uint32_t above = incl - seg;
    if (above < KK && incl >= KK) {
        uint32_t c = above;
        #pragma unroll
        for (int i = 15; i >= 0; --i) {
            if (c + h[i] >= KK) {
                tEst[b] = inv_orderable(((uint32_t)(tid * 16 + i)) << 20);
                break;
            }
            c += h[i];
        }
    }
}

// One block per (b, group of SPG samples). Fine-window selection.
template <int USE_WS>
__global__ __launch_bounds__(256) void topk_group_kernel(
    const float* __restrict__ x,
    const float* __restrict__ noise,
    const float* __restrict__ tEst,
    unsigned char* __restrict__ ws,      // [BB][NG][DD] u8
    float* __restrict__ outCounts)       // [BB][DD] f32 (fallback, pre-zeroed)
{
    const int tid  = threadIdx.x;
    const int bg   = blockIdx.x;
    const int b    = bg >> 5;            // / NG (NG=32)
    const int g    = bg & (NG - 1);
    const int lane = tid & 63;
    const int wid  = tid >> 6;

    __shared__ uint32_t hist[NBIN];      // 1 KB, one bin per thread
    __shared__ uint32_t counts[DD];      // 8 KB
    __shared__ uint32_t wWin[4], wTot[4];
    __shared__ float    cand_f[CAND_MAX];
    __shared__ uint32_t cand_d[CAND_MAX];
    __shared__ uint32_t candCnt[2];
    __shared__ uint32_t sh_tb, sh_R;

    // ---- init ----
    hist[tid] = 0u;
    const uint4 z = make_uint4(0u, 0u, 0u, 0u);
    uint4* c4 = (uint4*)counts;
    c4[tid] = z; c4[tid + 256] = z;
    if (tid == 0) { candCnt[0] = 0u; candCnt[1] = 0u; }

    const float lo    = tEst[b] - WHALF;
    const float scale = (float)NBIN / (2.0f * WHALF);   // 128

    // ---- x row -> registers (shared by all SPG samples) ----
    const float4* xr = (const float4*)(x + (size_t)b * DD);
    const float4 xv0 = xr[tid * 2 + 0];
    const float4 xv1 = xr[tid * 2 + 1];

    const float4* nbase =
        (const float4*)(noise + ((size_t)b * NS + (size_t)g * SPG) * DD);
    float4 nv0 = nbase[tid * 2 + 0];
    float4 nv1 = nbase[tid * 2 + 1];

    __syncthreads();

    for (int s = 0; s < SPG; ++s) {
        // ---- perturbed values (registers) ----
        float v[8];
        v[0] = fmaf(nv0.x, 0.05f, xv0.x);
        v[1] = fmaf(nv0.y, 0.05f, xv0.y);
        v[2] = fmaf(nv0.z, 0.05f, xv0.z);
        v[3] = fmaf(nv0.w, 0.05f, xv0.w);
        v[4] = fmaf(nv1.x, 0.05f, xv1.x);
        v[5] = fmaf(nv1.y, 0.05f, xv1.y);
        v[6] = fmaf(nv1.z, 0.05f, xv1.z);
        v[7] = fmaf(nv1.w, 0.05f, xv1.w);

        // ---- prefetch next sample's noise row ----
        if (s + 1 < SPG) {
            const float4* nr = nbase + (size_t)(s + 1) * (DD / 4);
            nv0 = nr[tid * 2 + 0];
            nv1 = nr[tid * 2 + 1];
        }

        // ---- bin into fine window; count above-window winners ----
        int rb[8];
        uint32_t w = 0;
        #pragma unroll
        for (int e = 0; e < 8; ++e) {
            if (v[e] >= lo) {
                int r = (int)((v[e] - lo) * scale);   // >= 0, trunc == floor
                rb[e] = r;
                if (r >= NBIN) ++w;
                else atomicAdd(&hist[r], 1u);
            } else {
                rb[e] = -1;                            // definite loser
            }
        }
        // wave-reduce above-window count
        #pragma unroll
        for (int st = 32; st >= 1; st >>= 1)
            w += __shfl_down(w, (unsigned)st, 64);
        if (lane == 0) wWin[wid] = w;
        __syncthreads();                               // B1

        if (tid == 0) {
            candCnt[(s + 1) & 1] = 0u;                 // reset other parity
            sh_tb = NBIN; sh_R = 0u;                   // safety default
        }

        const uint32_t W = wWin[0] + wWin[1] + wWin[2] + wWin[3];
        const uint32_t h = hist[tid];                  // own bin
        uint32_t sfx = h;
        #pragma unroll
        for (int st = 1; st < 64; st <<= 1) {
            uint32_t o = __shfl_down(sfx, (unsigned)st, 64);
            if (lane + st < 64) sfx += o;
        }
        if (lane == 0) wTot[wid] = sfx;
        __syncthreads();                               // B2
        uint32_t hi2 = 0;
        #pragma unroll
        for (int w2 = 0; w2 < 4; ++w2) if (w2 > wid) hi2 += wTot[w2];
        const uint32_t incl  = sfx + hi2 + W;  // elems >= own bin's lower edge
        const uint32_t above = incl - h;       // elems in strictly higher bins
        if (above < KK && incl >= KK) { sh_tb = (uint32_t)tid; sh_R = KK - above; }
        __syncthreads();                               // B3
        const int      tb  = (int)sh_tb;
        const uint32_t R   = sh_R;
        const uint32_t par = (uint32_t)(s & 1);

        // ---- classify + scatter-zero own bins ----
        #pragma unroll
        for (int e = 0; e < 8; ++e) {
            int r = rb[e];
            if (r > tb) {
                counts[tid * 8 + e] += 1u;             // exclusive owner
            } else if (r == tb) {
                uint32_t j = atomicAdd(&candCnt[par], 1u);
                if (j < CAND_MAX) { cand_f[j] = v[e]; cand_d[j] = (uint32_t)(tid * 8 + e); }
            }
        }
        #pragma unroll
        for (int e = 0; e < 8; ++e) {
            int r = rb[e];
            if (r >= 0 && r < NBIN) hist[r] = 0u;      // duplicates benign
        }
        __syncthreads();                               // B4

        // ---- exact rank-select top R among candidates (tie-break by d) ----
        uint32_t M = candCnt[par];
        if (M > CAND_MAX) M = CAND_MAX;
        for (uint32_t j = tid; j < M; j += 256) {
            float    vv = cand_f[j];
            uint32_t dj = cand_d[j];
            uint32_t r  = 0;
            for (uint32_t i = 0; i < M; ++i) {
                float vi = cand_f[i];
                r += (vi > vv) || (vi == vv && cand_d[i] < dj);
            }
            if (r < R) atomicAdd(&counts[dj], 1u);
        }
        // next sample's B1 orders rank-adds vs classify reads
    }
    __syncthreads();

    // ---- write group partial counts ----
    if (USE_WS) {
        uint32_t* w32 = (uint32_t*)(ws + ((size_t)b * NG + g) * DD);
        #pragma unroll
        for (int q = 0; q < 2; ++q) {
            uint32_t p = 0;
            #pragma unroll
            for (int e = 0; e < 4; ++e)
                p |= (counts[tid * 8 + q * 4 + e] & 0xFFu) << (8 * e);
            w32[tid * 2 + q] = p;
        }
    } else {
        float* rowOut = outCounts + (size_t)b * DD;
        #pragma unroll
        for (int e = 0; e < 8; ++e) {
            uint32_t c = counts[tid * 8 + e];
            if (c) atomicAdd(&rowOut[tid * 8 + e], (float)c);
        }
    }
}

// Sum NG u8 partials per (b,d), normalize, write both output halves.
__global__ __launch_bounds__(256) void reduce_kernel(
    const unsigned char* __restrict__ ws, float* __restrict__ out)
{
    int idx = blockIdx.x * 256 + threadIdx.x;  // 0 .. BB*DD/4-1
    int b   = idx / (DD / 4);
    int dq  = idx - b * (DD / 4);
    const unsigned char* base = ws + (size_t)b * NG * DD + (size_t)dq * 4;
    uint32_t s0 = 0, s1 = 0, s2 = 0, s3 = 0;
    #pragma unroll
    for (int g = 0; g < NG; ++g) {
        uint32_t p = *(const uint32_t*)(base + (size_t)g * DD);
        s0 += p & 0xFFu; s1 += (p >> 8) & 0xFFu;
        s2 += (p >> 16) & 0xFFu; s3 += (p >> 24) & 0xFFu;
    }
    const float inv = 1.0f / 256.0f;
    float4 t = make_float4(s0 * inv, s1 * inv, s2 * inv, s3 * inv);
    *(float4*)(out + (size_t)b * DD + dq * 4) = t;
    *(float4*)(out + (size_t)(BB * DD) + (size_t)b * DD + dq * 4) =
        make_float4(1.0f - t.x, 1.0f - t.y, 1.0f - t.z, 1.0f - t.w);
}

// Fallback finalize (only when ws is too small): counts -> (topk, 1-topk).
__global__ __launch_bounds__(256) void finalize_kernel(float* __restrict__ out) {
    int i = blockIdx.x * 256 + threadIdx.x;  // 0 .. BB*DD-1
    float t = out[i] * (1.0f / 256.0f);
    out[i] = t;
    out[BB * DD + i] = 1.0f - t;
}

extern "C" void kernel_launch(void* const* d_in, const int* in_sizes, int n_in,
                              void* d_out, int out_size, void* d_ws, size_t ws_size,
                              hipStream_t stream) {
    const float* x     = (const float*)d_in[0];
    const float* noise = (const float*)d_in[1];
    float* out = (float*)d_out;

    const size_t partials = (size_t)BB * NG * DD;           // 4 MB of u8
    if (ws_size >= partials + BB * sizeof(float)) {
        unsigned char* ws8 = (unsigned char*)d_ws;
        float* tEst = (float*)(ws8 + partials);
        thresh_kernel<<<BB, 256, 0, stream>>>(x, tEst);
        topk_group_kernel<1><<<BB * NG, 256, 0, stream>>>(x, noise, tEst, ws8, nullptr);
        reduce_kernel<<<(BB * DD / 4) / 256, 256, 0, stream>>>(ws8, out);
    } else {
        float* tEst = (float*)d_ws;                         // needs 256 B
        hipMemsetAsync(out, 0, (size_t)BB * DD * sizeof(float), stream);
        thresh_kernel<<<BB, 256, 0, stream>>>(x, tEst);
        topk_group_kernel<0><<<BB * NG, 256, 0, stream>>>(x, noise, tEst, nullptr, out);
        finalize_kernel<<<(BB * DD) / 256, 256, 0, stream>>>(out);
    }
}